// Round 20
// baseline (286.925 us; speedup 1.0000x reference)
//
#include <hip/hip_runtime.h>
#include <hip/hip_bf16.h>
#include <cstdint>

#define B_ 32
#define D_ 256
#define K_ 1024
#define N_TOK 32768
#define Z_ELEMS 8388608
#define OUT_IDX_OFF Z_ELEMS
#define OUT_LOSS_OFF (Z_ELEMS + N_TOK)

// ws layout (2.63 MB total — known-safe footprint):
//   [0,4096)             f32 cnorm[1024]
//   [4096,8192)          f32 partials[1024]
//   [8192,532480)        cb_frag bf16: chunk s=cblk*8+kc at s*8192; frag ct at +ct*1024+lane*16
//   [532480,2629632)     u32 top2[8 cblk][32768 tok][2]
#define WS_CNORM_OFF 0
#define WS_PART_OFF  4096
#define WS_CBF_OFF   8192
#define WS_TOP2_OFF  532480

#define MARGIN 1.25f

typedef __attribute__((ext_vector_type(8))) short short8v;
typedef __attribute__((ext_vector_type(4))) float f32x4;
typedef unsigned long long u64;

__device__ __forceinline__ unsigned short f2bf(float x) {
    unsigned u = __float_as_uint(x);
    return (unsigned short)((u + 0x7fffu + ((u >> 16) & 1u)) >> 16);  // RNE
}
__device__ __forceinline__ unsigned packf(float f) {
    unsigned u = __float_as_uint(f);
    return (u & 0x80000000u) ? ~u : (u | 0x80000000u);
}
__device__ __forceinline__ float unpackf(unsigned p) {
    unsigned u = (p & 0x80000000u) ? (p & 0x7fffffffu) : ~p;
    return __uint_as_float(u);
}

// ---------------- kernel 0: cnorm + cb -> bf16 fragment order (64 blocks) --------
__global__ __launch_bounds__(256)
void prep_kernel(const float* __restrict__ cb, float* __restrict__ cnorm,
                 unsigned char* __restrict__ cbf) {
    const int t = threadIdx.x;
    const int blk = blockIdx.x;  // 64 blocks
    {
        int k = blk * 16 + (t >> 4);
        int part = t & 15;
        const float4* row = reinterpret_cast<const float4*>(cb + k * D_);
        float s = 0.f;
#pragma unroll
        for (int j = 0; j < 4; ++j) {
            float4 v = row[part * 4 + j];
            s += v.x * v.x + v.y * v.y + v.z * v.z + v.w * v.w;
        }
        s += __shfl_xor(s, 1);
        s += __shfl_xor(s, 2);
        s += __shfl_xor(s, 4);
        s += __shfl_xor(s, 8);
        if (part == 0) cnorm[k] = s;
    }
#pragma unroll
    for (int w = 0; w < 2; ++w) {
        int g = blk * 512 + w * 256 + t;
        int lane = g & 63, ct = (g >> 6) & 7, kc = (g >> 9) & 7, cblk = g >> 12;
        int code = cblk * 128 + ct * 16 + (lane & 15);
        int d0 = kc * 32 + (lane >> 4) * 8;
        const float* src = cb + code * 256 + d0;
        float4 a = *reinterpret_cast<const float4*>(src);
        float4 b2 = *reinterpret_cast<const float4*>(src + 4);
        uint4 pk;
        pk.x = (unsigned)f2bf(a.x) | ((unsigned)f2bf(a.y) << 16);
        pk.y = (unsigned)f2bf(a.z) | ((unsigned)f2bf(a.w) << 16);
        pk.z = (unsigned)f2bf(b2.x) | ((unsigned)f2bf(b2.y) << 16);
        pk.w = (unsigned)f2bf(b2.z) | ((unsigned)f2bf(b2.w) << 16);
        *reinterpret_cast<uint4*>(cbf + (size_t)g * 16) = pk;
    }
}

// ---------------- kernel 1: MFMA screen, 128-token tile (2x A-reuse) ----------------
// 256 blocks x 256 thr (4 waves). Block = 128 tok x 1024 codes; wave wv = cblks {2wv,2wv+1}
// over all 128 tokens. Each A-fragment feeds 8 MFMAs (vs 4) -> grid A-loads halved.
__global__
void mm_kernel(const float* __restrict__ z, const unsigned char* __restrict__ cbf,
               const float* __restrict__ cnorm, unsigned* __restrict__ top2) {
    __shared__ __align__(16) unsigned char zfB[65536];  // 128 tok x 256 d bf16 fragments

    const int t = threadIdx.x;
    const int lane = t & 63;
    const int wv = t >> 6;
    const int blk = blockIdx.x;        // 0..255
    const int b = blk >> 3;
    const int hw0 = (blk & 7) << 7;    // 128 tokens
    const float* zb = z + ((size_t)b << 18) + hw0;

    {   // stage 128 tok x 256 d -> bf16 fragments (r11 formula, 8 token-groups)
        const int tok = t & 127;
        const int dseg = t >> 7;       // 2 segs x 128 d
#pragma unroll
        for (int u = 0; u < 16; ++u) {
            int d0 = dseg * 128 + u * 8;
            float v[8];
#pragma unroll
            for (int j = 0; j < 8; ++j) v[j] = zb[(size_t)(d0 + j) * 1024 + tok];
            uint4 pk;
            pk.x = (unsigned)f2bf(v[0]) | ((unsigned)f2bf(v[1]) << 16);
            pk.y = (unsigned)f2bf(v[2]) | ((unsigned)f2bf(v[3]) << 16);
            pk.z = (unsigned)f2bf(v[4]) | ((unsigned)f2bf(v[5]) << 16);
            pk.w = (unsigned)f2bf(v[6]) | ((unsigned)f2bf(v[7]) << 16);
            int kc = d0 >> 5;          // dseg*4 + (u>>2)
            *reinterpret_cast<uint4*>(zfB + (kc * 8 + (tok >> 4)) * 1024 +
                                      ((u & 3) * 16 + (tok & 15)) * 16) = pk;
        }
    }
    __syncthreads();

    const int rbase = (lane >> 4) << 2;
    const unsigned char* zrd = zfB + lane * 16;

    for (int cb2 = 0; cb2 < 2; ++cb2) {
        const int cblk = wv * 2 + cb2;
        const unsigned char* abase = cbf + (size_t)cblk * 65536 + lane * 16;

        unsigned k1[8], k2[8];
#pragma unroll
        for (int nt = 0; nt < 8; ++nt) { k1[nt] = 0xFFFFFFFFu; k2[nt] = 0xFFFFFFFFu; }

        for (int p = 0; p < 2; ++p) {
            f32x4 acc[4][8];
#pragma unroll
            for (int mt = 0; mt < 4; ++mt)
#pragma unroll
                for (int nt = 0; nt < 8; ++nt) acc[mt][nt] = (f32x4){0.f, 0.f, 0.f, 0.f};

#pragma unroll
            for (int kc = 0; kc < 8; ++kc) {
                short8v bfv[8];
#pragma unroll
                for (int nt = 0; nt < 8; ++nt)
                    bfv[nt] = *reinterpret_cast<const short8v*>(zrd + (kc * 8 + nt) * 1024);
                short8v af[4];
#pragma unroll
                for (int mt = 0; mt < 4; ++mt)
                    af[mt] = *reinterpret_cast<const short8v*>(
                        abase + (kc * 8 + p * 4 + mt) * 1024);
#pragma unroll
                for (int mt = 0; mt < 4; ++mt)
#pragma unroll
                    for (int nt = 0; nt < 8; ++nt)
                        acc[mt][nt] = __builtin_amdgcn_mfma_f32_16x16x32_bf16(
                            af[mt], bfv[nt], acc[mt][nt], 0, 0, 0);
            }

            // fold this phase's 64 codes; cnorm hoisted per (mt,r), reused across 8 nt
#pragma unroll
            for (int mt = 0; mt < 4; ++mt) {
#pragma unroll
                for (int r = 0; r < 4; ++r) {
                    const int code = cblk * 128 + (p * 4 + mt) * 16 + rbase + r;
                    const float cn = cnorm[code];
                    const unsigned kb = (unsigned)code;
#pragma unroll
                    for (int nt = 0; nt < 8; ++nt) {
                        float d2a = fmaf(-2.0f, acc[mt][nt][r], cn);
                        unsigned key = (packf(d2a) & 0xFFFFFC00u) | kb;
                        if (key < k1[nt]) { k2[nt] = k1[nt]; k1[nt] = key; }
                        else if (key < k2[nt]) { k2[nt] = key; }
                    }
                }
            }
        }

#pragma unroll
        for (int nt = 0; nt < 8; ++nt) {
            unsigned a1 = k1[nt], a2 = k2[nt];
#pragma unroll
            for (int x = 16; x <= 32; x <<= 1) {
                unsigned o1 = __shfl_xor(a1, x);
                unsigned o2 = __shfl_xor(a2, x);
                unsigned n1, n2;
                if (a1 < o1) { n1 = a1; n2 = (a2 < o1) ? a2 : o1; }
                else         { n1 = o1; n2 = (o2 < a1) ? o2 : a1; }
                a1 = n1; a2 = n2;
            }
            if (lane < 16) {
                int token = blk * 128 + nt * 16 + lane;
                *reinterpret_cast<uint2*>(top2 + ((size_t)cblk * N_TOK + token) * 2) =
                    make_uint2(a1, a2);
            }
        }
    }
}

// ---------------- kernel 2: fused exact refine + gather + loss partials ----------------
__global__ __launch_bounds__(256)
void refgather_kernel(const float* __restrict__ z, const float* __restrict__ cb,
                      const float* __restrict__ cnorm, const unsigned* __restrict__ top2,
                      float* __restrict__ out, float* __restrict__ partials) {
    __shared__ float zsm[32][261];
    __shared__ float crows[32][257];
    __shared__ int cand[32][16];
    __shared__ int cnt[32];
    __shared__ u64 bestk[32];
    __shared__ int sidx[32];
    __shared__ float red[256];
    __shared__ int maxc;

    const int t = threadIdx.x;
    const int bh = blockIdx.x;
    const int b = bh >> 5, h = bh & 31;
    const int n0 = b * 1024 + h * 32;
    const int w = t & 31, dg = t >> 5;

    {
        const float* zp = z + ((size_t)b << 18) + h * 32 + w;
#pragma unroll
        for (int i = 0; i < 32; ++i) {
            int d = dg * 32 + i;
            zsm[w][d] = zp[(size_t)d * 1024];
        }
    }
    if (t < 32) cnt[t] = 0;
    if (t == 0) maxc = 0;
    __syncthreads();

    const int tk = t >> 3, l8 = t & 7;
    {
        uint2 kk = *reinterpret_cast<const uint2*>(
            top2 + ((size_t)l8 * N_TOK + (n0 + tk)) * 2);
        unsigned mn = kk.x;
#pragma unroll
        for (int x = 1; x < 8; x <<= 1) {
            unsigned o = __shfl_xor(mn, x);
            if (o < mn) mn = o;
        }
        float thr = unpackf(mn & 0xFFFFFC00u) + MARGIN;
        float da = unpackf(kk.x & 0xFFFFFC00u);
        if (da <= thr) { int p = atomicAdd(&cnt[tk], 1); cand[tk][p] = (int)(kk.x & 1023u); }
        float db = unpackf(kk.y & 0xFFFFFC00u);
        if (db <= thr) { int p = atomicAdd(&cnt[tk], 1); cand[tk][p] = (int)(kk.y & 1023u); }
    }
    __syncthreads();
    if (t < 32) atomicMax(&maxc, cnt[t]);
    __syncthreads();

    const int mc = maxc;
    u64 best = ~0ull;
    for (int ci = 0; ci < mc; ++ci) {
        if (ci < cnt[tk]) {
            int k = cand[tk][ci];
            const float* crow = cb + (size_t)k * 256;
            float s = 0.f;
#pragma unroll
            for (int j = 0; j < 32; ++j) {
                int d = j * 8 + l8;
                s = fmaf(zsm[tk][d], crow[d], s);
            }
#pragma unroll
            for (int x = 1; x < 8; x <<= 1) s += __shfl_xor(s, x);
            float d2 = cnorm[k] - 2.f * s;
            u64 key = ((u64)packf(d2) << 32) | (unsigned)k;
            if (key < best) best = key;
        }
    }
    if (l8 == 0) bestk[tk] = best;
    __syncthreads();
    if (t < 32) {
        int k = (int)(bestk[t] & 1023ull);
        sidx[t] = k;
        out[OUT_IDX_OFF + n0 + t] = (float)k;
    }
    __syncthreads();
    {
        const int r = t & 31, q = t >> 5;
        const float4* src = reinterpret_cast<const float4*>(cb + (size_t)sidx[r] * 256 + q * 32);
#pragma unroll
        for (int j = 0; j < 8; ++j) {
            float4 v = src[j];
            int d = q * 32 + j * 4;
            crows[r][d] = v.x; crows[r][d + 1] = v.y;
            crows[r][d + 2] = v.z; crows[r][d + 3] = v.w;
        }
    }
    __syncthreads();
    float accl = 0.f;
    float* orow = out + ((size_t)b << 18) + h * 32 + w;
#pragma unroll
    for (int i = 0; i < 32; ++i) {
        const int d = dg * 32 + i;
        const float cv = crows[w][d];
        const float zv = zsm[w][d];
        orow[(size_t)d * 1024] = cv;
        const float df = cv - zv;
        accl += df * df;
    }
    red[t] = accl;
    __syncthreads();
    for (int s = 128; s > 0; s >>= 1) {
        if (t < s) red[t] += red[t + s];
        __syncthreads();
    }
    if (t == 0) partials[bh] = red[0];
}

// ---------------- kernel 3: deterministic final loss reduction ----------------
__global__ __launch_bounds__(256) void loss_kernel(const float* __restrict__ partials,
                                                   float* __restrict__ out) {
    __shared__ float red[256];
    const int t = threadIdx.x;
    float s = partials[t] + partials[t + 256] + partials[t + 512] + partials[t + 768];
    red[t] = s;
    __syncthreads();
    for (int st = 128; st > 0; st >>= 1) {
        if (t < st) red[t] += red[t + st];
        __syncthreads();
    }
    if (t == 0) out[OUT_LOSS_OFF] = red[0] * (1.25f / (float)Z_ELEMS);
}

extern "C" void kernel_launch(void* const* d_in, const int* in_sizes, int n_in,
                              void* d_out, int out_size, void* d_ws, size_t ws_size,
                              hipStream_t stream) {
    const float* z = (const float*)d_in[0];   // [32,256,32,32] f32
    const float* cb = (const float*)d_in[1];  // [1024,256] f32
    float* out = (float*)d_out;
    float* cnorm = (float*)((char*)d_ws + WS_CNORM_OFF);
    float* partials = (float*)((char*)d_ws + WS_PART_OFF);
    unsigned char* cbf = (unsigned char*)d_ws + WS_CBF_OFF;
    unsigned* top2 = (unsigned*)((char*)d_ws + WS_TOP2_OFF);

    prep_kernel<<<64, 256, 0, stream>>>(cb, cnorm, cbf);
    mm_kernel<<<256, 256, 0, stream>>>(z, cbf, cnorm, top2);
    refgather_kernel<<<1024, 256, 0, stream>>>(z, cb, cnorm, top2, out, partials);
    loss_kernel<<<1, 256, 0, stream>>>(partials, out);
}

// Round 21
// 74.269 us; speedup vs baseline: 3.8633x; 3.8633x over previous
//
#include <hip/hip_runtime.h>
#include <hip/hip_bf16.h>
#include <cstdint>

#define B_ 32
#define D_ 256
#define K_ 1024
#define N_TOK 32768
#define Z_ELEMS 8388608
#define OUT_IDX_OFF Z_ELEMS
#define OUT_LOSS_OFF (Z_ELEMS + N_TOK)

// ws layout (2.63 MB total — known-safe footprint):
//   [0,4096)             f32 cnorm[1024]
//   [4096,8192)          f32 partials[1024]
//   [8192,532480)        cb_frag bf16: chunk s=cblk*8+kc at s*8192; frag ct at +ct*1024+lane*16
//   [532480,2629632)     u32 top2[8 cblk][32768 tok][2]
#define WS_CNORM_OFF 0
#define WS_PART_OFF  4096
#define WS_CBF_OFF   8192
#define WS_TOP2_OFF  532480

#define MARGIN 1.25f

typedef __attribute__((ext_vector_type(8))) short short8v;
typedef __attribute__((ext_vector_type(4))) float f32x4;
typedef unsigned long long u64;

__device__ __forceinline__ unsigned short f2bf(float x) {
    unsigned u = __float_as_uint(x);
    return (unsigned short)((u + 0x7fffu + ((u >> 16) & 1u)) >> 16);  // RNE
}
__device__ __forceinline__ unsigned packf(float f) {
    unsigned u = __float_as_uint(f);
    return (u & 0x80000000u) ? ~u : (u | 0x80000000u);
}
__device__ __forceinline__ float unpackf(unsigned p) {
    unsigned u = (p & 0x80000000u) ? (p & 0x7fffffffu) : ~p;
    return __uint_as_float(u);
}

// ---------------- kernel 0: cnorm + cb -> bf16 fragment order (64 blocks) --------
__global__ __launch_bounds__(256)
void prep_kernel(const float* __restrict__ cb, float* __restrict__ cnorm,
                 unsigned char* __restrict__ cbf) {
    const int t = threadIdx.x;
    const int blk = blockIdx.x;  // 64 blocks
    {
        int k = blk * 16 + (t >> 4);
        int part = t & 15;
        const float4* row = reinterpret_cast<const float4*>(cb + k * D_);
        float s = 0.f;
#pragma unroll
        for (int j = 0; j < 4; ++j) {
            float4 v = row[part * 4 + j];
            s += v.x * v.x + v.y * v.y + v.z * v.z + v.w * v.w;
        }
        s += __shfl_xor(s, 1);
        s += __shfl_xor(s, 2);
        s += __shfl_xor(s, 4);
        s += __shfl_xor(s, 8);
        if (part == 0) cnorm[k] = s;
    }
#pragma unroll
    for (int w = 0; w < 2; ++w) {
        int g = blk * 512 + w * 256 + t;
        int lane = g & 63, ct = (g >> 6) & 7, kc = (g >> 9) & 7, cblk = g >> 12;
        int code = cblk * 128 + ct * 16 + (lane & 15);
        int d0 = kc * 32 + (lane >> 4) * 8;
        const float* src = cb + code * 256 + d0;
        float4 a = *reinterpret_cast<const float4*>(src);
        float4 b2 = *reinterpret_cast<const float4*>(src + 4);
        uint4 pk;
        pk.x = (unsigned)f2bf(a.x) | ((unsigned)f2bf(a.y) << 16);
        pk.y = (unsigned)f2bf(a.z) | ((unsigned)f2bf(a.w) << 16);
        pk.z = (unsigned)f2bf(b2.x) | ((unsigned)f2bf(b2.y) << 16);
        pk.w = (unsigned)f2bf(b2.z) | ((unsigned)f2bf(b2.w) << 16);
        *reinterpret_cast<uint4*>(cbf + (size_t)g * 16) = pk;
    }
}

// ---------------- kernel 1: MFMA screen, 128-token tile (2x A-reuse) ----------------
// 256 blocks x 256 thr (4 waves). Block = 128 tok x 1024 codes; wave wv = cblks {2wv,2wv+1}
// over all 128 tokens. Each A-fragment feeds 8 MFMAs (vs 4) -> grid A-loads halved.
// __launch_bounds__(256) WITHOUT min-waves: the only clean-compile mode (r6/7/13/20 law).
__global__ __launch_bounds__(256)
void mm_kernel(const float* __restrict__ z, const unsigned char* __restrict__ cbf,
               const float* __restrict__ cnorm, unsigned* __restrict__ top2) {
    __shared__ __align__(16) unsigned char zfB[65536];  // 128 tok x 256 d bf16 fragments

    const int t = threadIdx.x;
    const int lane = t & 63;
    const int wv = t >> 6;
    const int blk = blockIdx.x;        // 0..255
    const int b = blk >> 3;
    const int hw0 = (blk & 7) << 7;    // 128 tokens
    const float* zb = z + ((size_t)b << 18) + hw0;

    {   // stage 128 tok x 256 d -> bf16 fragments (r11 formula, 8 token-groups)
        const int tok = t & 127;
        const int dseg = t >> 7;       // 2 segs x 128 d
#pragma unroll
        for (int u = 0; u < 16; ++u) {
            int d0 = dseg * 128 + u * 8;
            float v[8];
#pragma unroll
            for (int j = 0; j < 8; ++j) v[j] = zb[(size_t)(d0 + j) * 1024 + tok];
            uint4 pk;
            pk.x = (unsigned)f2bf(v[0]) | ((unsigned)f2bf(v[1]) << 16);
            pk.y = (unsigned)f2bf(v[2]) | ((unsigned)f2bf(v[3]) << 16);
            pk.z = (unsigned)f2bf(v[4]) | ((unsigned)f2bf(v[5]) << 16);
            pk.w = (unsigned)f2bf(v[6]) | ((unsigned)f2bf(v[7]) << 16);
            int kc = d0 >> 5;          // dseg*4 + (u>>2)
            *reinterpret_cast<uint4*>(zfB + (kc * 8 + (tok >> 4)) * 1024 +
                                      ((u & 3) * 16 + (tok & 15)) * 16) = pk;
        }
    }
    __syncthreads();

    const int rbase = (lane >> 4) << 2;
    const unsigned char* zrd = zfB + lane * 16;

    for (int cb2 = 0; cb2 < 2; ++cb2) {
        const int cblk = wv * 2 + cb2;
        const unsigned char* abase = cbf + (size_t)cblk * 65536 + lane * 16;

        unsigned k1[8], k2[8];
#pragma unroll
        for (int nt = 0; nt < 8; ++nt) { k1[nt] = 0xFFFFFFFFu; k2[nt] = 0xFFFFFFFFu; }

        for (int p = 0; p < 2; ++p) {
            f32x4 acc[4][8];
#pragma unroll
            for (int mt = 0; mt < 4; ++mt)
#pragma unroll
                for (int nt = 0; nt < 8; ++nt) acc[mt][nt] = (f32x4){0.f, 0.f, 0.f, 0.f};

#pragma unroll
            for (int kc = 0; kc < 8; ++kc) {
                short8v bfv[8];
#pragma unroll
                for (int nt = 0; nt < 8; ++nt)
                    bfv[nt] = *reinterpret_cast<const short8v*>(zrd + (kc * 8 + nt) * 1024);
                short8v af[4];
#pragma unroll
                for (int mt = 0; mt < 4; ++mt)
                    af[mt] = *reinterpret_cast<const short8v*>(
                        abase + (kc * 8 + p * 4 + mt) * 1024);
#pragma unroll
                for (int mt = 0; mt < 4; ++mt)
#pragma unroll
                    for (int nt = 0; nt < 8; ++nt)
                        acc[mt][nt] = __builtin_amdgcn_mfma_f32_16x16x32_bf16(
                            af[mt], bfv[nt], acc[mt][nt], 0, 0, 0);
            }

            // fold this phase's 64 codes; cnorm hoisted per (mt,r), reused across 8 nt
#pragma unroll
            for (int mt = 0; mt < 4; ++mt) {
#pragma unroll
                for (int r = 0; r < 4; ++r) {
                    const int code = cblk * 128 + (p * 4 + mt) * 16 + rbase + r;
                    const float cn = cnorm[code];
                    const unsigned kb = (unsigned)code;
#pragma unroll
                    for (int nt = 0; nt < 8; ++nt) {
                        float d2a = fmaf(-2.0f, acc[mt][nt][r], cn);
                        unsigned key = (packf(d2a) & 0xFFFFFC00u) | kb;
                        if (key < k1[nt]) { k2[nt] = k1[nt]; k1[nt] = key; }
                        else if (key < k2[nt]) { k2[nt] = key; }
                    }
                }
            }
        }

#pragma unroll
        for (int nt = 0; nt < 8; ++nt) {
            unsigned a1 = k1[nt], a2 = k2[nt];
#pragma unroll
            for (int x = 16; x <= 32; x <<= 1) {
                unsigned o1 = __shfl_xor(a1, x);
                unsigned o2 = __shfl_xor(a2, x);
                unsigned n1, n2;
                if (a1 < o1) { n1 = a1; n2 = (a2 < o1) ? a2 : o1; }
                else         { n1 = o1; n2 = (o2 < a1) ? o2 : a1; }
                a1 = n1; a2 = n2;
            }
            if (lane < 16) {
                int token = blk * 128 + nt * 16 + lane;
                *reinterpret_cast<uint2*>(top2 + ((size_t)cblk * N_TOK + token) * 2) =
                    make_uint2(a1, a2);
            }
        }
    }
}

// ---------------- kernel 2: fused exact refine + gather + loss partials ----------------
__global__ __launch_bounds__(256)
void refgather_kernel(const float* __restrict__ z, const float* __restrict__ cb,
                      const float* __restrict__ cnorm, const unsigned* __restrict__ top2,
                      float* __restrict__ out, float* __restrict__ partials) {
    __shared__ float zsm[32][261];
    __shared__ float crows[32][257];
    __shared__ int cand[32][16];
    __shared__ int cnt[32];
    __shared__ u64 bestk[32];
    __shared__ int sidx[32];
    __shared__ float red[256];
    __shared__ int maxc;

    const int t = threadIdx.x;
    const int bh = blockIdx.x;
    const int b = bh >> 5, h = bh & 31;
    const int n0 = b * 1024 + h * 32;
    const int w = t & 31, dg = t >> 5;

    {
        const float* zp = z + ((size_t)b << 18) + h * 32 + w;
#pragma unroll
        for (int i = 0; i < 32; ++i) {
            int d = dg * 32 + i;
            zsm[w][d] = zp[(size_t)d * 1024];
        }
    }
    if (t < 32) cnt[t] = 0;
    if (t == 0) maxc = 0;
    __syncthreads();

    const int tk = t >> 3, l8 = t & 7;
    {
        uint2 kk = *reinterpret_cast<const uint2*>(
            top2 + ((size_t)l8 * N_TOK + (n0 + tk)) * 2);
        unsigned mn = kk.x;
#pragma unroll
        for (int x = 1; x < 8; x <<= 1) {
            unsigned o = __shfl_xor(mn, x);
            if (o < mn) mn = o;
        }
        float thr = unpackf(mn & 0xFFFFFC00u) + MARGIN;
        float da = unpackf(kk.x & 0xFFFFFC00u);
        if (da <= thr) { int p = atomicAdd(&cnt[tk], 1); cand[tk][p] = (int)(kk.x & 1023u); }
        float db = unpackf(kk.y & 0xFFFFFC00u);
        if (db <= thr) { int p = atomicAdd(&cnt[tk], 1); cand[tk][p] = (int)(kk.y & 1023u); }
    }
    __syncthreads();
    if (t < 32) atomicMax(&maxc, cnt[t]);
    __syncthreads();

    const int mc = maxc;
    u64 best = ~0ull;
    for (int ci = 0; ci < mc; ++ci) {
        if (ci < cnt[tk]) {
            int k = cand[tk][ci];
            const float* crow = cb + (size_t)k * 256;
            float s = 0.f;
#pragma unroll
            for (int j = 0; j < 32; ++j) {
                int d = j * 8 + l8;
                s = fmaf(zsm[tk][d], crow[d], s);
            }
#pragma unroll
            for (int x = 1; x < 8; x <<= 1) s += __shfl_xor(s, x);
            float d2 = cnorm[k] - 2.f * s;
            u64 key = ((u64)packf(d2) << 32) | (unsigned)k;
            if (key < best) best = key;
        }
    }
    if (l8 == 0) bestk[tk] = best;
    __syncthreads();
    if (t < 32) {
        int k = (int)(bestk[t] & 1023ull);
        sidx[t] = k;
        out[OUT_IDX_OFF + n0 + t] = (float)k;
    }
    __syncthreads();
    {
        const int r = t & 31, q = t >> 5;
        const float4* src = reinterpret_cast<const float4*>(cb + (size_t)sidx[r] * 256 + q * 32);
#pragma unroll
        for (int j = 0; j < 8; ++j) {
            float4 v = src[j];
            int d = q * 32 + j * 4;
            crows[r][d] = v.x; crows[r][d + 1] = v.y;
            crows[r][d + 2] = v.z; crows[r][d + 3] = v.w;
        }
    }
    __syncthreads();
    float accl = 0.f;
    float* orow = out + ((size_t)b << 18) + h * 32 + w;
#pragma unroll
    for (int i = 0; i < 32; ++i) {
        const int d = dg * 32 + i;
        const float cv = crows[w][d];
        const float zv = zsm[w][d];
        orow[(size_t)d * 1024] = cv;
        const float df = cv - zv;
        accl += df * df;
    }
    red[t] = accl;
    __syncthreads();
    for (int s = 128; s > 0; s >>= 1) {
        if (t < s) red[t] += red[t + s];
        __syncthreads();
    }
    if (t == 0) partials[bh] = red[0];
}

// ---------------- kernel 3: deterministic final loss reduction ----------------
__global__ __launch_bounds__(256) void loss_kernel(const float* __restrict__ partials,
                                                   float* __restrict__ out) {
    __shared__ float red[256];
    const int t = threadIdx.x;
    float s = partials[t] + partials[t + 256] + partials[t + 512] + partials[t + 768];
    red[t] = s;
    __syncthreads();
    for (int st = 128; st > 0; st >>= 1) {
        if (t < st) red[t] += red[t + st];
        __syncthreads();
    }
    if (t == 0) out[OUT_LOSS_OFF] = red[0] * (1.25f / (float)Z_ELEMS);
}

extern "C" void kernel_launch(void* const* d_in, const int* in_sizes, int n_in,
                              void* d_out, int out_size, void* d_ws, size_t ws_size,
                              hipStream_t stream) {
    const float* z = (const float*)d_in[0];   // [32,256,32,32] f32
    const float* cb = (const float*)d_in[1];  // [1024,256] f32
    float* out = (float*)d_out;
    float* cnorm = (float*)((char*)d_ws + WS_CNORM_OFF);
    float* partials = (float*)((char*)d_ws + WS_PART_OFF);
    unsigned char* cbf = (unsigned char*)d_ws + WS_CBF_OFF;
    unsigned* top2 = (unsigned*)((char*)d_ws + WS_TOP2_OFF);

    prep_kernel<<<64, 256, 0, stream>>>(cb, cnorm, cbf);
    mm_kernel<<<256, 256, 0, stream>>>(z, cbf, cnorm, top2);
    refgather_kernel<<<1024, 256, 0, stream>>>(z, cb, cnorm, top2, out, partials);
    loss_kernel<<<1, 256, 0, stream>>>(partials, out);
}